// Round 1
// baseline (360.166 us; speedup 1.0000x reference)
//
#include <hip/hip_runtime.h>
#include <hip/hip_bf16.h>

#define UU 2048
#define DM 32
#define TB 128   // tile edge
#define NB 16    // batch
#define NP 3     // pairs

// ---------------------------------------------------------------------------
// Stage 1: for each (pair, b), compute
//   S1[j] = sum_i exp(f1_i . f2_j)   (column sums, denominator of N1)
//   S2[i] = sum_j exp(f1_i . f2_j)   (row sums, denominator of N2)
// Tiled 128x128 per block, 256 threads, 8x8 register blocking.
// ---------------------------------------------------------------------------
__global__ __launch_bounds__(256) void stage1_sums(
    const float* __restrict__ a, const float* __restrict__ v,
    const float* __restrict__ l, float* __restrict__ S1,
    float* __restrict__ S2) {
  const int p = blockIdx.z >> 4;   // pair 0..2
  const int b = blockIdx.z & 15;   // batch
  const float* f1 = (p == 2) ? v : a;   // p0:(a,v) p1:(a,l) p2:(v,l)
  const float* f2 = (p == 0) ? v : l;
  f1 += (size_t)b * UU * DM;
  f2 += (size_t)b * UU * DM;
  const int i0 = blockIdx.y * TB;
  const int j0 = blockIdx.x * TB;

  // stride 36 floats: 16B-aligned rows; compute reads are <=2-way conflicts
  __shared__ float t1[TB][36];
  __shared__ float t2[TB][36];

  const int t = threadIdx.x;

  // Load both 128x32 tiles. Flat index -> fully coalesced float4 global loads.
#pragma unroll
  for (int pass = 0; pass < 4; ++pass) {
    int fi = pass * 1024 + t * 4;
    int row = fi >> 5;
    int col = fi & 31;
    *(float4*)&t1[row][col] =
        *(const float4*)(f1 + (size_t)(i0 + row) * DM + col);
    *(float4*)&t2[row][col] =
        *(const float4*)(f2 + (size_t)(j0 + row) * DM + col);
  }
  __syncthreads();

  const int ti = t & 15;   // i-group: rows i = ti + 16*r
  const int tj = t >> 4;   // j-group: cols j = tj + 16*s

  float acc[8][8];
#pragma unroll
  for (int r = 0; r < 8; ++r)
#pragma unroll
    for (int s = 0; s < 8; ++s) acc[r][s] = 0.f;

  for (int d4 = 0; d4 < DM; d4 += 4) {
    float4 av[8], bv[8];
#pragma unroll
    for (int r = 0; r < 8; ++r) av[r] = *(const float4*)&t1[ti + 16 * r][d4];
#pragma unroll
    for (int s = 0; s < 8; ++s) bv[s] = *(const float4*)&t2[tj + 16 * s][d4];
#pragma unroll
    for (int r = 0; r < 8; ++r)
#pragma unroll
      for (int s = 0; s < 8; ++s) {
        acc[r][s] = fmaf(av[r].x, bv[s].x, acc[r][s]);
        acc[r][s] = fmaf(av[r].y, bv[s].y, acc[r][s]);
        acc[r][s] = fmaf(av[r].z, bv[s].z, acc[r][s]);
        acc[r][s] = fmaf(av[r].w, bv[s].w, acc[r][s]);
      }
  }

  float rowsum[8], colsum[8];
#pragma unroll
  for (int s = 0; s < 8; ++s) colsum[s] = 0.f;
#pragma unroll
  for (int r = 0; r < 8; ++r) {
    float rs = 0.f;
#pragma unroll
    for (int s = 0; s < 8; ++s) {
      float e = __expf(acc[r][s]);
      rs += e;
      colsum[s] += e;
    }
    rowsum[r] = rs;
  }

  __syncthreads();  // tiles dead; reuse LDS for reduction
  float* red1 = &t1[0][0];  // colsum partials: [ti][128]
  float* red2 = &t2[0][0];  // rowsum partials: [tj][128]
#pragma unroll
  for (int r = 0; r < 8; ++r) red2[tj * 128 + (ti + 16 * r)] = rowsum[r];
#pragma unroll
  for (int s = 0; s < 8; ++s) red1[ti * 128 + (tj + 16 * s)] = colsum[s];
  __syncthreads();

  if (t < 128) {
    float s1 = 0.f, s2 = 0.f;
#pragma unroll
    for (int w = 0; w < 16; ++w) {
      s2 += red2[w * 128 + t];
      s1 += red1[w * 128 + t];
    }
    const size_t base = (size_t)(p * NB + b) * UU;
    atomicAdd(&S2[base + i0 + t], s2);
    atomicAdd(&S1[base + j0 + t], s1);
  }
}

// ---------------------------------------------------------------------------
// Stage 2: per (pair, b, dir) compute the 32-vector
//   dir0: O1 = sum_j exp(f1_0 . f2_j)/S1[j] * f2_j ; Bi[b][p][0:32]  = O1*f1_0
//   dir1: O2 = sum_i exp(f1_i . f2_0)/S2[i] * f1_i ; Bi[b][p][32:64] = O2*f2_0
// ---------------------------------------------------------------------------
__global__ __launch_bounds__(256) void stage2_O(
    const float* __restrict__ a, const float* __restrict__ v,
    const float* __restrict__ l, const float* __restrict__ S1,
    const float* __restrict__ S2, float* __restrict__ Bi) {
  const int idx = blockIdx.x;
  const int dir = idx & 1;
  const int pb = idx >> 1;
  const int p = pb >> 4, b = pb & 15;
  const float* f1 = (p == 2) ? v : a;
  const float* f2 = (p == 0) ? v : l;
  f1 += (size_t)b * UU * DM;
  f2 += (size_t)b * UU * DM;
  const float* qrow = (dir == 0) ? f1 : f2;  // row 0 (query + output scale)
  const float* rows = (dir == 0) ? f2 : f1;
  const float* den = ((dir == 0) ? S1 : S2) + (size_t)pb * UU;

  __shared__ float qv[DM];
  __shared__ float wred[4][DM];
  const int t = threadIdx.x;
  if (t < DM) qv[t] = qrow[t];
  __syncthreads();

  float accd[DM];
#pragma unroll
  for (int d = 0; d < DM; ++d) accd[d] = 0.f;

  for (int r = t; r < UU; r += 256) {
    const float4* rp = (const float4*)(rows + (size_t)r * DM);
    float rv[DM];
#pragma unroll
    for (int q = 0; q < 8; ++q) {
      float4 x = rp[q];
      rv[4 * q + 0] = x.x;
      rv[4 * q + 1] = x.y;
      rv[4 * q + 2] = x.z;
      rv[4 * q + 3] = x.w;
    }
    float dot = 0.f;
#pragma unroll
    for (int d = 0; d < DM; ++d) dot = fmaf(rv[d], qv[d], dot);
    float w = __expf(dot) / den[r];
#pragma unroll
    for (int d = 0; d < DM; ++d) accd[d] = fmaf(w, rv[d], accd[d]);
  }

  const int lane = t & 63, wave = t >> 6;
#pragma unroll
  for (int d = 0; d < DM; ++d) {
    float vs = accd[d];
#pragma unroll
    for (int off = 32; off > 0; off >>= 1) vs += __shfl_down(vs, off, 64);
    if (lane == 0) wred[wave][d] = vs;
  }
  __syncthreads();
  if (t < DM) {
    float o = wred[0][t] + wred[1][t] + wred[2][t] + wred[3][t];
    Bi[(size_t)(b * NP + p) * 64 + dir * DM + t] = o * qrow[t];
  }
}

// ---------------------------------------------------------------------------
// Stage 3: Ci = tanh(Bi@fc1^T + fc1_b)@fc2^T ; alpha = softmax over batch;
// CCA_i[b,:] = sum_k alpha[b,k] * Bi[b,k,:].  One wave (64 threads).
// ---------------------------------------------------------------------------
__global__ __launch_bounds__(64) void stage3_head(
    const float* __restrict__ Bi, const float* __restrict__ fc1w,
    const float* __restrict__ fc1b, const float* __restrict__ fc2w,
    float* __restrict__ CCA) {
  const int h = threadIdx.x;  // 0..63
  __shared__ float CiS[NB * NP];
  __shared__ float denomk[NP];

  for (int bk = 0; bk < NB * NP; ++bk) {
    const float* brow = Bi + bk * 64;
    float x = fc1b[h];
#pragma unroll 8
    for (int c = 0; c < 64; ++c) x = fmaf(brow[c], fc1w[h * 64 + c], x);
    float vv = tanhf(x) * fc2w[h];
#pragma unroll
    for (int off = 32; off > 0; off >>= 1) vv += __shfl_down(vv, off, 64);
    if (h == 0) CiS[bk] = vv;
  }
  __syncthreads();
  if (h < NP) {
    float s = 0.f;
    for (int b = 0; b < NB; ++b) s += __expf(CiS[b * NP + h]);
    denomk[h] = s;
  }
  __syncthreads();
  for (int b = 0; b < NB; ++b) {
    float s = 0.f;
#pragma unroll
    for (int k = 0; k < NP; ++k)
      s += __expf(CiS[b * NP + k]) / denomk[k] * Bi[(b * NP + k) * 64 + h];
    CCA[b * 64 + h] = s;
  }
}

// ---------------------------------------------------------------------------
// Stage 4: broadcast CCA_i[b,:] to out[b, u, :] for all u.  float4 stores.
// ---------------------------------------------------------------------------
__global__ __launch_bounds__(256) void stage4_bcast(
    const float* __restrict__ CCA, float4* __restrict__ out) {
  const int gid = blockIdx.x * 256 + threadIdx.x;  // 0 .. 524287 (float4 idx)
  const int c4 = gid & 15;        // 64 floats = 16 float4 per row
  const int b = gid >> 15;        // / (2048*16)
  const float4* cc = (const float4*)CCA;
  out[gid] = cc[b * 16 + c4];
}

extern "C" void kernel_launch(void* const* d_in, const int* in_sizes, int n_in,
                              void* d_out, int out_size, void* d_ws,
                              size_t ws_size, hipStream_t stream) {
  const float* a = (const float*)d_in[0];
  const float* v = (const float*)d_in[1];
  const float* l = (const float*)d_in[2];
  const float* fc1w = (const float*)d_in[3];
  const float* fc1b = (const float*)d_in[4];
  const float* fc2w = (const float*)d_in[5];
  float* out = (float*)d_out;

  // workspace layout (floats)
  float* S1 = (float*)d_ws;              // 3*16*2048
  float* S2 = S1 + NP * NB * UU;         // 3*16*2048
  float* Bi = S2 + NP * NB * UU;         // 16*3*64
  float* CCA = Bi + NB * NP * 64;        // 16*64

  // zero the atomic accumulators (ws is poisoned 0xAA before each call)
  hipMemsetAsync(d_ws, 0, (size_t)(2 * NP * NB * UU) * sizeof(float), stream);

  stage1_sums<<<dim3(UU / TB, UU / TB, NP * NB), 256, 0, stream>>>(a, v, l, S1,
                                                                   S2);
  stage2_O<<<dim3(NP * NB * 2), 256, 0, stream>>>(a, v, l, S1, S2, Bi);
  stage3_head<<<dim3(1), 64, 0, stream>>>(Bi, fc1w, fc1b, fc2w, CCA);
  stage4_bcast<<<dim3(2048), 256, 0, stream>>>(CCA, (float4*)out);
}

// Round 2
// 286.037 us; speedup vs baseline: 1.2592x; 1.2592x over previous
//
#include <hip/hip_runtime.h>
#include <hip/hip_bf16.h>

#define UU 2048
#define DM 32
#define TB 128   // tile edge
#define NB 16    // batch
#define NP 3     // pairs

// ---------------------------------------------------------------------------
// Stage 1: for each (pair, b), compute
//   S1[j] = sum_i exp(f1_i . f2_j)   (column sums, denominator of N1)
//   S2[i] = sum_j exp(f1_i . f2_j)   (row sums, denominator of N2)
// Tiled 128x128 per block, 256 threads, 8x8 register blocking.
// __launch_bounds__(256,2): VGPR cap 256 so the 64-float accumulator tile
// stays in registers (at default bounds the compiler capped at 76 VGPR and
// spilled acc to scratch: WRITE_SIZE 12.3MB vs 0.8MB legit).
// ---------------------------------------------------------------------------
__global__ __launch_bounds__(256, 2) void stage1_sums(
    const float* __restrict__ a, const float* __restrict__ v,
    const float* __restrict__ l, float* __restrict__ S1,
    float* __restrict__ S2) {
  const int p = blockIdx.z >> 4;   // pair 0..2
  const int b = blockIdx.z & 15;   // batch
  const float* f1 = (p == 2) ? v : a;   // p0:(a,v) p1:(a,l) p2:(v,l)
  const float* f2 = (p == 0) ? v : l;
  f1 += (size_t)b * UU * DM;
  f2 += (size_t)b * UU * DM;
  const int i0 = blockIdx.y * TB;
  const int j0 = blockIdx.x * TB;

  // stride 36 floats: 16B-aligned rows; compute reads are <=2-way conflicts
  __shared__ float t1[TB][36];
  __shared__ float t2[TB][36];

  const int t = threadIdx.x;

  // Load both 128x32 tiles. Flat index -> fully coalesced float4 global loads.
#pragma unroll
  for (int pass = 0; pass < 4; ++pass) {
    int fi = pass * 1024 + t * 4;
    int row = fi >> 5;
    int col = fi & 31;
    *(float4*)&t1[row][col] =
        *(const float4*)(f1 + (size_t)(i0 + row) * DM + col);
    *(float4*)&t2[row][col] =
        *(const float4*)(f2 + (size_t)(j0 + row) * DM + col);
  }
  __syncthreads();

  const int ti = t & 15;   // i-group: rows i = ti + 16*r
  const int tj = t >> 4;   // j-group: cols j = tj + 16*s

  float acc[8][8];
#pragma unroll
  for (int r = 0; r < 8; ++r)
#pragma unroll
    for (int s = 0; s < 8; ++s) acc[r][s] = 0.f;

  for (int d4 = 0; d4 < DM; d4 += 4) {
    float4 av[8], bv[8];
#pragma unroll
    for (int r = 0; r < 8; ++r) av[r] = *(const float4*)&t1[ti + 16 * r][d4];
#pragma unroll
    for (int s = 0; s < 8; ++s) bv[s] = *(const float4*)&t2[tj + 16 * s][d4];
#pragma unroll
    for (int r = 0; r < 8; ++r)
#pragma unroll
      for (int s = 0; s < 8; ++s) {
        acc[r][s] = fmaf(av[r].x, bv[s].x, acc[r][s]);
        acc[r][s] = fmaf(av[r].y, bv[s].y, acc[r][s]);
        acc[r][s] = fmaf(av[r].z, bv[s].z, acc[r][s]);
        acc[r][s] = fmaf(av[r].w, bv[s].w, acc[r][s]);
      }
  }

  float rowsum[8], colsum[8];
#pragma unroll
  for (int s = 0; s < 8; ++s) colsum[s] = 0.f;
#pragma unroll
  for (int r = 0; r < 8; ++r) {
    float rs = 0.f;
#pragma unroll
    for (int s = 0; s < 8; ++s) {
      float e = __expf(acc[r][s]);
      rs += e;
      colsum[s] += e;
    }
    rowsum[r] = rs;
  }

  __syncthreads();  // tiles dead; reuse LDS for reduction
  float* red1 = &t1[0][0];  // colsum partials: [ti][128]
  float* red2 = &t2[0][0];  // rowsum partials: [tj][128]
#pragma unroll
  for (int r = 0; r < 8; ++r) red2[tj * 128 + (ti + 16 * r)] = rowsum[r];
#pragma unroll
  for (int s = 0; s < 8; ++s) red1[ti * 128 + (tj + 16 * s)] = colsum[s];
  __syncthreads();

  if (t < 128) {
    float s1 = 0.f, s2 = 0.f;
#pragma unroll
    for (int w = 0; w < 16; ++w) {
      s2 += red2[w * 128 + t];
      s1 += red1[w * 128 + t];
    }
    const size_t base = (size_t)(p * NB + b) * UU;
    atomicAdd(&S2[base + i0 + t], s2);
    atomicAdd(&S1[base + j0 + t], s1);
  }
}

// ---------------------------------------------------------------------------
// Stage 2: per (pair, b, dir, chunk-of-256-rows) accumulate the 32-vector
//   dir0: O1 += sum_j exp(f1_0 . f2_j)/S1[j] * f2_j
//   dir1: O2 += sum_i exp(f1_i . f2_0)/S2[i] * f1_i
// into OO via atomicAdd. 768 blocks (was 96 -> latency-bound). The *qrow
// scaling happens in stage3.
// ---------------------------------------------------------------------------
__global__ __launch_bounds__(256) void stage2_O(
    const float* __restrict__ a, const float* __restrict__ v,
    const float* __restrict__ l, const float* __restrict__ S1,
    const float* __restrict__ S2, float* __restrict__ OO) {
  const int idx = blockIdx.x;
  const int chunk = idx & 7;
  const int pd = idx >> 3;       // (pb, dir) flat
  const int dir = pd & 1;
  const int pb = pd >> 1;
  const int p = pb >> 4, b = pb & 15;
  const float* f1 = (p == 2) ? v : a;
  const float* f2 = (p == 0) ? v : l;
  f1 += (size_t)b * UU * DM;
  f2 += (size_t)b * UU * DM;
  const float* qrow = (dir == 0) ? f1 : f2;  // row 0 of the "query" side
  const float* rows = (dir == 0) ? f2 : f1;
  const float* den = ((dir == 0) ? S1 : S2) + (size_t)pb * UU;

  __shared__ float qv[DM];
  __shared__ float wred[4][DM];
  const int t = threadIdx.x;
  if (t < DM) qv[t] = qrow[t];
  __syncthreads();

  const int r = chunk * 256 + t;   // exactly one row per thread
  const float4* rp = (const float4*)(rows + (size_t)r * DM);
  float rv[DM];
#pragma unroll
  for (int q = 0; q < 8; ++q) {
    float4 x = rp[q];
    rv[4 * q + 0] = x.x;
    rv[4 * q + 1] = x.y;
    rv[4 * q + 2] = x.z;
    rv[4 * q + 3] = x.w;
  }
  float dot = 0.f;
#pragma unroll
  for (int d = 0; d < DM; ++d) dot = fmaf(rv[d], qv[d], dot);
  const float w = __expf(dot) / den[r];

  const int lane = t & 63, wave = t >> 6;
#pragma unroll
  for (int d = 0; d < DM; ++d) {
    float vs = w * rv[d];
#pragma unroll
    for (int off = 32; off > 0; off >>= 1) vs += __shfl_down(vs, off, 64);
    if (lane == 0) wred[wave][d] = vs;
  }
  __syncthreads();
  if (t < DM) {
    float o = wred[0][t] + wred[1][t] + wred[2][t] + wred[3][t];
    atomicAdd(&OO[(size_t)pd * DM + t], o);
  }
}

// ---------------------------------------------------------------------------
// Stage 3 (1024 threads, one block):
//   Bi[b][p][dir*32+d] = OO[(p*16+b)*2+dir][d] * qrow[d]   (held in LDS)
//   Ci = tanh(Bi@fc1^T + fc1_b)@fc2^T ; alpha = softmax over batch;
//   CCA[b,:] = sum_k alpha[b,k] * Bi[b,k,:]
// ---------------------------------------------------------------------------
__global__ __launch_bounds__(1024) void stage3_head(
    const float* __restrict__ a, const float* __restrict__ v,
    const float* __restrict__ l, const float* __restrict__ OO,
    const float* __restrict__ fc1w, const float* __restrict__ fc1b,
    const float* __restrict__ fc2w, float* __restrict__ CCA) {
  const int t = threadIdx.x;
  __shared__ float BiL[NB * NP * 64];
  __shared__ float CiS[NB * NP];
  __shared__ float denomk[NP];

  // Phase A: Bi = OO * qrow
#pragma unroll
  for (int iter = 0; iter < 3; ++iter) {
    int m = iter * 1024 + t;          // 0..3071
    int bk = m >> 6;                  // b*NP + p
    int h = m & 63;
    int b = bk / NP, p = bk - b * NP;
    int dir = h >> 5, hd = h & 31;
    const float* base = (dir == 0) ? ((p == 2) ? v : a) : ((p == 0) ? v : l);
    float q = base[(size_t)b * UU * DM + hd];
    int pb = p * NB + b;
    BiL[bk * 64 + h] = OO[(pb * 2 + dir) * DM + hd] * q;
  }
  __syncthreads();

  // Phase B: Ci[bk]; wave g handles bk = g + 16*iter
  const int h = t & 63;
  const int g = t >> 6;  // 0..15
#pragma unroll
  for (int iter = 0; iter < 3; ++iter) {
    int bk = g + 16 * iter;
    float x = fc1b[h];
#pragma unroll 8
    for (int c = 0; c < 64; ++c) x = fmaf(BiL[bk * 64 + c], fc1w[h * 64 + c], x);
    float vv = tanhf(x) * fc2w[h];
#pragma unroll
    for (int off = 32; off > 0; off >>= 1) vv += __shfl_down(vv, off, 64);
    if (h == 0) CiS[bk] = vv;
  }
  __syncthreads();

  if (t < NP) {
    float s = 0.f;
    for (int b = 0; b < NB; ++b) s += __expf(CiS[b * NP + t]);
    denomk[t] = s;
  }
  __syncthreads();

  // Phase C: CCA[b*64+h]; 16 groups x 64 threads = all 1024
  {
    int b = g;
    float s = 0.f;
#pragma unroll
    for (int k = 0; k < NP; ++k)
      s += __expf(CiS[b * NP + k]) / denomk[k] * BiL[(b * NP + k) * 64 + h];
    CCA[b * 64 + h] = s;
  }
}

// ---------------------------------------------------------------------------
// Stage 4: broadcast CCA[b,:] to out[b, u, :] for all u.  float4 stores.
// ---------------------------------------------------------------------------
__global__ __launch_bounds__(256) void stage4_bcast(
    const float* __restrict__ CCA, float4* __restrict__ out) {
  const int gid = blockIdx.x * 256 + threadIdx.x;  // 0 .. 524287 (float4 idx)
  const int c4 = gid & 15;        // 64 floats = 16 float4 per row
  const int b = gid >> 15;        // / (2048*16)
  const float4* cc = (const float4*)CCA;
  out[gid] = cc[b * 16 + c4];
}

extern "C" void kernel_launch(void* const* d_in, const int* in_sizes, int n_in,
                              void* d_out, int out_size, void* d_ws,
                              size_t ws_size, hipStream_t stream) {
  const float* a = (const float*)d_in[0];
  const float* v = (const float*)d_in[1];
  const float* l = (const float*)d_in[2];
  const float* fc1w = (const float*)d_in[3];
  const float* fc1b = (const float*)d_in[4];
  const float* fc2w = (const float*)d_in[5];
  float* out = (float*)d_out;

  // workspace layout (floats)
  float* S1 = (float*)d_ws;              // 3*16*2048
  float* S2 = S1 + NP * NB * UU;         // 3*16*2048
  float* OO = S2 + NP * NB * UU;         // 96*32 partial O sums
  float* CCA = OO + NP * NB * 2 * DM;    // 16*64

  // zero the atomic accumulators (ws is poisoned 0xAA before each call)
  hipMemsetAsync(d_ws, 0,
                 (size_t)(2 * NP * NB * UU + NP * NB * 2 * DM) * sizeof(float),
                 stream);

  stage1_sums<<<dim3(UU / TB, UU / TB, NP * NB), 256, 0, stream>>>(a, v, l, S1,
                                                                   S2);
  stage2_O<<<dim3(NP * NB * 2 * 8), 256, 0, stream>>>(a, v, l, S1, S2, OO);
  stage3_head<<<dim3(1), 1024, 0, stream>>>(a, v, l, OO, fc1w, fc1b, fc2w,
                                            CCA);
  stage4_bcast<<<dim3(2048), 256, 0, stream>>>(CCA, (float4*)out);
}

// Round 3
// 191.258 us; speedup vs baseline: 1.8831x; 1.4956x over previous
//
#include <hip/hip_runtime.h>
#include <hip/hip_bf16.h>

#define UU 2048
#define DM 32
#define TB 128   // tile edge
#define NB 16    // batch
#define NP 3     // pairs

typedef short short8_t __attribute__((ext_vector_type(8)));
typedef short short4_t __attribute__((ext_vector_type(4)));
typedef float float4_t __attribute__((ext_vector_type(4)));

// split x into bf16 hi (truncate) + bf16 lo (truncate of remainder).
// hi+lo carries ~24 bits of mantissa; dropped lo*lo term in the dot is
// ~2^-16 relative -> dot abs err ~5e-4 vs absmax threshold 7e-2.
__device__ inline void split8(const float4 x0, const float4 x1, short8_t& h,
                              short8_t& lo) {
  float xs[8] = {x0.x, x0.y, x0.z, x0.w, x1.x, x1.y, x1.z, x1.w};
#pragma unroll
  for (int i = 0; i < 8; ++i) {
    unsigned u = __float_as_uint(xs[i]);
    h[i] = (short)(u >> 16);
    float hif = __uint_as_float(u & 0xffff0000u);
    lo[i] = (short)(__float_as_uint(xs[i] - hif) >> 16);
  }
}

// ---------------------------------------------------------------------------
// Stage 1 (MFMA bf16x3): for each (pair, b) compute
//   S1[j] = sum_i exp(f1_i . f2_j),  S2[i] = sum_j exp(f1_i . f2_j)
// 128x128 region/block, 4 waves; wave w covers rows [w*32, w*32+32).
// Per 16x16 tile: 3x mfma_f32_16x16x32_bf16 (hi*hi + hi*lo + lo*hi).
// C/D layout: col=lane&15, row=(lane>>4)*4+reg  [m89-verified].
// LDS rows padded to 40 shorts (80B): 16B-aligned b128 frags, <=2-way banks.
// ---------------------------------------------------------------------------
__global__ __launch_bounds__(256, 3) void stage1_sums(
    const float* __restrict__ a, const float* __restrict__ v,
    const float* __restrict__ l, float* __restrict__ S1,
    float* __restrict__ S2) {
  const int p = blockIdx.z >> 4;   // pair 0..2
  const int b = blockIdx.z & 15;   // batch
  const float* f1 = (p == 2) ? v : a;   // p0:(a,v) p1:(a,l) p2:(v,l)
  const float* f2 = (p == 0) ? v : l;
  f1 += (size_t)b * UU * DM;
  f2 += (size_t)b * UU * DM;
  const int i0 = blockIdx.y * TB;
  const int j0 = blockIdx.x * TB;

  __shared__ __align__(16) short Ah[TB][40];
  __shared__ __align__(16) short Al[TB][40];
  __shared__ __align__(16) short Bh[TB][40];
  __shared__ __align__(16) short Bl[TB][40];
  __shared__ float ldsC[4][TB];

  const int t = threadIdx.x;

  // Staging: 8 consecutive floats per (thread, pass, strip) -> hi/lo bf16.
#pragma unroll
  for (int pass = 0; pass < 2; ++pass) {
    int f8 = pass * 256 + t;     // 0..511 (8-float unit)
    int row = f8 >> 2;           // 0..127
    int col = (f8 & 3) * 8;      // 0,8,16,24
    {
      const float* src = f1 + (size_t)(i0 + row) * DM + col;
      short8_t h, lo;
      split8(*(const float4*)src, *(const float4*)(src + 4), h, lo);
      *(short8_t*)&Ah[row][col] = h;
      *(short8_t*)&Al[row][col] = lo;
    }
    {
      const float* src = f2 + (size_t)(j0 + row) * DM + col;
      short8_t h, lo;
      split8(*(const float4*)src, *(const float4*)(src + 4), h, lo);
      *(short8_t*)&Bh[row][col] = h;
      *(short8_t*)&Bl[row][col] = lo;
    }
  }
  __syncthreads();

  const int lane = t & 63, w = t >> 6;
  const int lm = lane & 15, lq = lane >> 4;
  const int k0 = lq * 8;

  // A-frags for this wave's two row-tiles (hi & lo)
  short8_t a_h[2], a_l[2];
#pragma unroll
  for (int rt = 0; rt < 2; ++rt) {
    int m = w * 32 + rt * 16 + lm;
    a_h[rt] = *(short8_t*)&Ah[m][k0];
    a_l[rt] = *(short8_t*)&Al[m][k0];
  }

  float rowp[2][4];
  float colp[8];
#pragma unroll
  for (int rt = 0; rt < 2; ++rt)
#pragma unroll
    for (int r = 0; r < 4; ++r) rowp[rt][r] = 0.f;
#pragma unroll
  for (int ct = 0; ct < 8; ++ct) colp[ct] = 0.f;

#pragma unroll
  for (int ct = 0; ct < 8; ++ct) {
    int n = ct * 16 + lm;
    short8_t b_h = *(short8_t*)&Bh[n][k0];
    short8_t b_l = *(short8_t*)&Bl[n][k0];
#pragma unroll
    for (int rt = 0; rt < 2; ++rt) {
      float4_t c = {0.f, 0.f, 0.f, 0.f};
      c = __builtin_amdgcn_mfma_f32_16x16x32_bf16(a_h[rt], b_h, c, 0, 0, 0);
      c = __builtin_amdgcn_mfma_f32_16x16x32_bf16(a_h[rt], b_l, c, 0, 0, 0);
      c = __builtin_amdgcn_mfma_f32_16x16x32_bf16(a_l[rt], b_h, c, 0, 0, 0);
      float e0 = __expf(c[0]);
      float e1 = __expf(c[1]);
      float e2 = __expf(c[2]);
      float e3 = __expf(c[3]);
      rowp[rt][0] += e0;
      rowp[rt][1] += e1;
      rowp[rt][2] += e2;
      rowp[rt][3] += e3;
      colp[ct] += (e0 + e1) + (e2 + e3);
    }
  }

  const size_t base = (size_t)(p * NB + b) * UU;

  // Row (i) sums: reduce across the 16 lanes of each quarter (cols 0..15)
#pragma unroll
  for (int rt = 0; rt < 2; ++rt)
#pragma unroll
    for (int r = 0; r < 4; ++r) {
      float vv = rowp[rt][r];
      vv += __shfl_xor(vv, 1, 64);
      vv += __shfl_xor(vv, 2, 64);
      vv += __shfl_xor(vv, 4, 64);
      vv += __shfl_xor(vv, 8, 64);
      if (lm == 0)
        atomicAdd(&S2[base + i0 + w * 32 + rt * 16 + lq * 4 + r], vv);
    }

  // Col (j) sums: reduce across quarters (rows), then across waves via LDS
#pragma unroll
  for (int ct = 0; ct < 8; ++ct) {
    float vv = colp[ct];
    vv += __shfl_xor(vv, 16, 64);
    vv += __shfl_xor(vv, 32, 64);
    if (lane < 16) ldsC[w][ct * 16 + lane] = vv;
  }
  __syncthreads();
  if (t < TB) {
    float s = ldsC[0][t] + ldsC[1][t] + ldsC[2][t] + ldsC[3][t];
    atomicAdd(&S1[base + j0 + t], s);
  }
}

// ---------------------------------------------------------------------------
// Stage 2: per (pair, b, dir, chunk-of-256-rows) accumulate the 32-vector
//   dir0: O1 += sum_j exp(f1_0 . f2_j)/S1[j] * f2_j
//   dir1: O2 += sum_i exp(f1_i . f2_0)/S2[i] * f1_i
// into OO via atomicAdd. qrow scaling happens in stage3.
// ---------------------------------------------------------------------------
__global__ __launch_bounds__(256) void stage2_O(
    const float* __restrict__ a, const float* __restrict__ v,
    const float* __restrict__ l, const float* __restrict__ S1,
    const float* __restrict__ S2, float* __restrict__ OO) {
  const int idx = blockIdx.x;
  const int chunk = idx & 7;
  const int pd = idx >> 3;       // (pb, dir) flat
  const int dir = pd & 1;
  const int pb = pd >> 1;
  const int p = pb >> 4, b = pb & 15;
  const float* f1 = (p == 2) ? v : a;
  const float* f2 = (p == 0) ? v : l;
  f1 += (size_t)b * UU * DM;
  f2 += (size_t)b * UU * DM;
  const float* qrow = (dir == 0) ? f1 : f2;  // row 0 of the "query" side
  const float* rows = (dir == 0) ? f2 : f1;
  const float* den = ((dir == 0) ? S1 : S2) + (size_t)pb * UU;

  __shared__ float qv[DM];
  __shared__ float wred[4][DM];
  const int t = threadIdx.x;
  if (t < DM) qv[t] = qrow[t];
  __syncthreads();

  const int r = chunk * 256 + t;   // exactly one row per thread
  const float4* rp = (const float4*)(rows + (size_t)r * DM);
  float rv[DM];
#pragma unroll
  for (int q = 0; q < 8; ++q) {
    float4 x = rp[q];
    rv[4 * q + 0] = x.x;
    rv[4 * q + 1] = x.y;
    rv[4 * q + 2] = x.z;
    rv[4 * q + 3] = x.w;
  }
  float dot = 0.f;
#pragma unroll
  for (int d = 0; d < DM; ++d) dot = fmaf(rv[d], qv[d], dot);
  const float w = __expf(dot) / den[r];

  const int lane = t & 63, wave = t >> 6;
#pragma unroll
  for (int d = 0; d < DM; ++d) {
    float vs = w * rv[d];
#pragma unroll
    for (int off = 32; off > 0; off >>= 1) vs += __shfl_down(vs, off, 64);
    if (lane == 0) wred[wave][d] = vs;
  }
  __syncthreads();
  if (t < DM) {
    float o = wred[0][t] + wred[1][t] + wred[2][t] + wred[3][t];
    atomicAdd(&OO[(size_t)pd * DM + t], o);
  }
}

// ---------------------------------------------------------------------------
// Stage 3 (1024 threads, one block):
//   Bi[b][p][dir*32+d] = OO[(p*16+b)*2+dir][d] * qrow[d]   (held in LDS)
//   Ci = tanh(Bi@fc1^T + fc1_b)@fc2^T ; alpha = softmax over batch;
//   CCA[b,:] = sum_k alpha[b,k] * Bi[b,k,:]
// ---------------------------------------------------------------------------
__global__ __launch_bounds__(1024) void stage3_head(
    const float* __restrict__ a, const float* __restrict__ v,
    const float* __restrict__ l, const float* __restrict__ OO,
    const float* __restrict__ fc1w, const float* __restrict__ fc1b,
    const float* __restrict__ fc2w, float* __restrict__ CCA) {
  const int t = threadIdx.x;
  __shared__ float BiL[NB * NP * 64];
  __shared__ float CiS[NB * NP];
  __shared__ float denomk[NP];

  // Phase A: Bi = OO * qrow
#pragma unroll
  for (int iter = 0; iter < 3; ++iter) {
    int m = iter * 1024 + t;          // 0..3071
    int bk = m >> 6;                  // b*NP + p
    int h = m & 63;
    int b = bk / NP, p = bk - b * NP;
    int dir = h >> 5, hd = h & 31;
    const float* base = (dir == 0) ? ((p == 2) ? v : a) : ((p == 0) ? v : l);
    float q = base[(size_t)b * UU * DM + hd];
    int pb = p * NB + b;
    BiL[bk * 64 + h] = OO[(pb * 2 + dir) * DM + hd] * q;
  }
  __syncthreads();

  // Phase B: Ci[bk]; wave g handles bk = g + 16*iter
  const int h = t & 63;
  const int g = t >> 6;  // 0..15
#pragma unroll
  for (int iter = 0; iter < 3; ++iter) {
    int bk = g + 16 * iter;
    float x = fc1b[h];
#pragma unroll 8
    for (int c = 0; c < 64; ++c) x = fmaf(BiL[bk * 64 + c], fc1w[h * 64 + c], x);
    float vv = tanhf(x) * fc2w[h];
#pragma unroll
    for (int off = 32; off > 0; off >>= 1) vv += __shfl_down(vv, off, 64);
    if (h == 0) CiS[bk] = vv;
  }
  __syncthreads();

  if (t < NP) {
    float s = 0.f;
    for (int b = 0; b < NB; ++b) s += __expf(CiS[b * NP + t]);
    denomk[t] = s;
  }
  __syncthreads();

  // Phase C: CCA[b*64+h]; 16 groups x 64 threads = all 1024
  {
    int b = g;
    float s = 0.f;
#pragma unroll
    for (int k = 0; k < NP; ++k)
      s += __expf(CiS[b * NP + k]) / denomk[k] * BiL[(b * NP + k) * 64 + h];
    CCA[b * 64 + h] = s;
  }
}

// ---------------------------------------------------------------------------
// Stage 4: broadcast CCA[b,:] to out[b, u, :] for all u.  float4 stores.
// ---------------------------------------------------------------------------
__global__ __launch_bounds__(256) void stage4_bcast(
    const float* __restrict__ CCA, float4* __restrict__ out) {
  const int gid = blockIdx.x * 256 + threadIdx.x;  // 0 .. 524287 (float4 idx)
  const int c4 = gid & 15;        // 64 floats = 16 float4 per row
  const int b = gid >> 15;        // / (2048*16)
  const float4* cc = (const float4*)CCA;
  out[gid] = cc[b * 16 + c4];
}

extern "C" void kernel_launch(void* const* d_in, const int* in_sizes, int n_in,
                              void* d_out, int out_size, void* d_ws,
                              size_t ws_size, hipStream_t stream) {
  const float* a = (const float*)d_in[0];
  const float* v = (const float*)d_in[1];
  const float* l = (const float*)d_in[2];
  const float* fc1w = (const float*)d_in[3];
  const float* fc1b = (const float*)d_in[4];
  const float* fc2w = (const float*)d_in[5];
  float* out = (float*)d_out;

  // workspace layout (floats)
  float* S1 = (float*)d_ws;              // 3*16*2048
  float* S2 = S1 + NP * NB * UU;         // 3*16*2048
  float* OO = S2 + NP * NB * UU;         // 96*32 partial O sums
  float* CCA = OO + NP * NB * 2 * DM;    // 16*64

  // zero the atomic accumulators (ws is poisoned 0xAA before each call)
  hipMemsetAsync(d_ws, 0,
                 (size_t)(2 * NP * NB * UU + NP * NB * 2 * DM) * sizeof(float),
                 stream);

  stage1_sums<<<dim3(UU / TB, UU / TB, NP * NB), 256, 0, stream>>>(a, v, l, S1,
                                                                   S2);
  stage2_O<<<dim3(NP * NB * 2 * 8), 256, 0, stream>>>(a, v, l, S1, S2, OO);
  stage3_head<<<dim3(1), 1024, 0, stream>>>(a, v, l, OO, fc1w, fc1b, fc2w,
                                            CCA);
  stage4_bcast<<<dim3(2048), 256, 0, stream>>>(CCA, (float4*)out);
}